// Round 23
// baseline (167.769 us; speedup 1.0000x reference)
//
#include <hip/hip_runtime.h>
#include <math.h>

typedef __bf16 bf16;
typedef __bf16 bf16x8 __attribute__((ext_vector_type(8)));
typedef __bf16 bf16x4 __attribute__((ext_vector_type(4)));
typedef float  f32x4  __attribute__((ext_vector_type(4)));

union bfu { bf16x8 h; uint4 u; };

#define NSAMP 64
#define DIMC 192
#define SAMP_ELEMS 196608
#define M_TOK 65536

// ---- workspace layout (bytes) ----
constexpr size_t OFF_PART1  = 0;
constexpr size_t OFF_PART2  = 8192;
constexpr size_t OFF_BIASFV = 40960;
constexpr size_t OFF_WFV    = 43008;                // fragment-packed Wfv (147456 B)
constexpr size_t OFF_WPJ    = OFF_WFV + 147456;     // fragment-packed Wproj (73728 B)
constexpr size_t OFF_W1P    = OFF_WPJ + 73728;      // fragment-packed W1 (294912 B)
constexpr size_t OFF_W2P    = OFF_W1P + 294912;     // fragment-packed W2 (294912 B)
constexpr size_t OFF_R      = 1048576;
constexpr size_t OFF_FV     = OFF_R;
constexpr size_t OFF_Y      = OFF_R + 50331648;
constexpr size_t OFF_X1     = OFF_R + 100663296;

// ---------------- fused weight-prep + GN1 stats ----------------
// Blocks [0,576): weight prep (incl. Wpjp). Blocks [576,1600): GN1 stats over x.
__global__ __launch_bounds__(256) void prep_stats(
    const float* __restrict__ f_w, const float* __restrict__ v_w,
    const float* __restrict__ proj_w,
    const float* __restrict__ fc1_w, const float* __restrict__ fc2_w,
    const float* __restrict__ f_b, const float* __restrict__ v_b,
    bf16* __restrict__ Wfvp, bf16* __restrict__ Wpjp,
    bf16* __restrict__ W1p, bf16* __restrict__ W2p,
    float* __restrict__ biasfv,
    const float* __restrict__ X, float2* __restrict__ part)
{
    if (blockIdx.x >= 576) {
        const int blk = blockIdx.x - 576;
        const int b = blk >> 4, seg = blk & 15;
        const float4* p = (const float4*)(X + (size_t)b * SAMP_ELEMS + (size_t)seg * 12288);
        float s = 0.f, q = 0.f;
        for (int i = threadIdx.x; i < 3072; i += 256) {
            float4 v = p[i];
            s += v.x + v.y + v.z + v.w;
            q += v.x * v.x + v.y * v.y + v.z * v.z + v.w * v.w;
        }
        __shared__ float bs[256], bq[256];
        const int t = threadIdx.x;
        bs[t] = s; bq[t] = q; __syncthreads();
        for (int off = 128; off > 0; off >>= 1) {
            if (t < off) { bs[t] += bs[t + off]; bq[t] += bq[t + off]; }
            __syncthreads();
        }
        if (t == 0) part[b * 16 + seg] = make_float2(bs[0], bq[0]);
        return;
    }

    const int i = blockIdx.x * 256 + threadIdx.x;
    if (i < 73728) {
        const int e = i & 7, l = (i >> 3) & 63, f = i >> 9;
        const int ks = f % 6, wnf = f / 6;
        const int o = wnf * 16 + (l & 15);
        const int k = ks * 32 + (l >> 4) * 8 + e;
        Wfvp[i] = (bf16)(o < 192 ? f_w[o * 192 + k] : v_w[(o - 192) * 192 + k]);
    }
    if (i < 36864) {
        const int e = i & 7, l = (i >> 3) & 63, f = i >> 9;
        const int ks = f % 6, wnf = f / 6;
        const int o = wnf * 16 + (l & 15);
        const int k = ks * 32 + (l >> 4) * 8 + e;
        Wpjp[i] = (bf16)proj_w[o * 192 + k];
    }
    if (i < 147456) {
        const int e = i & 7, l = (i >> 3) & 63, f = i >> 9;
        const int ks = f % 6, pwj = f / 6;
        const int o = (pwj >> 2) * 64 + (pwj & 3) * 16 + (l & 15);
        const int k = ks * 32 + (l >> 4) * 8 + e;
        W1p[i] = (bf16)fc1_w[k * 768 + o];
    }
    if (i < 147456) {
        const int e = i & 7, l = (i >> 3) & 63, g = i >> 9;
        const int ks = g & 1, g1 = g >> 1;
        const int bqi = g1 % 3, jcw = g1 / 3;
        const int o = (jcw & 3) * 48 + bqi * 16 + (l & 15);
        const int k = (jcw >> 2) * 64 + ks * 32 + (l >> 4) * 8 + e;
        W2p[i] = (bf16)fc2_w[k * 192 + o];
    }
    if (i < 384) biasfv[i] = i < 192 ? f_b[i] : v_b[i - 192];
}

__device__ inline float2 gn_mv_n(const float2* __restrict__ part, int b, int n)
{
    float s = 0.f, q = 0.f;
    for (int i = 0; i < n; ++i) { float2 v = part[b * n + i]; s += v.x; q += v.y; }
    const float mean = s * (1.f / (float)SAMP_ELEMS);
    const float var = q * (1.f / (float)SAMP_ELEMS) - mean * mean;
    float2 r; r.x = mean; r.y = rsqrtf(var + 1e-5f);
    return r;
}

// ---------------- fused GN1 + f/v conv GEMM (R20-verified) ----------------
__global__ __launch_bounds__(512) void gemm_fv3(
    const float* __restrict__ X, const float2* __restrict__ part,
    const float* __restrict__ gw, const float* __restrict__ gb,
    const bf16* __restrict__ Wfvp, const float* __restrict__ bias,
    bf16* __restrict__ outb)
{
    __shared__ uint4 sA[64 * 24];
    const int t = threadIdx.x;
    const int m0 = blockIdx.x * 64;
    const int bb = m0 >> 10, p0 = m0 & 1023;
    const int lane = t & 63, wave = t >> 6;
    const int wm = wave >> 2, wn = wave & 3;
    const int lm = lane & 15, hi = lane >> 4;
    const float2 mv = gn_mv_n(part, bb, 16);

    bf16* sab = (bf16*)sA;
    for (int i = t; i < 3072; i += 512) {
        const int c = i >> 4, pq = i & 15;
        const float4 v = *(const float4*)(X + ((size_t)bb * DIMC + c) * 1024 + p0 + pq * 4);
        const float scale = gw[c] * mv.y;
        const float shift = gb[c] - mv.x * scale;
        const int ci = c >> 3, co = c & 7;
#pragma unroll
        for (int j = 0; j < 4; ++j) {
            const int r = pq * 4 + j;
            sab[(r * 24 + (ci ^ (r & 7))) * 8 + co] = (bf16)((&v.x)[j] * scale + shift);
        }
    }
    __syncthreads();

    const bf16x8* fa = (const bf16x8*)sA;
    const bf16x8* fw = (const bf16x8*)Wfvp;
    const int rA0 = wm * 32 + lm, rA1 = rA0 + 16;

    f32x4 acc[2][6] = {};
    bf16x8 wf[6];
#pragma unroll
    for (int nf = 0; nf < 6; ++nf)
        wf[nf] = fw[((wn * 6 + nf) * 6 + 0) * 64 + lane];

#pragma unroll
    for (int ks = 0; ks < 6; ++ks) {
        bf16x8 wfn[6];
        if (ks < 5) {
#pragma unroll
            for (int nf = 0; nf < 6; ++nf)
                wfn[nf] = fw[((wn * 6 + nf) * 6 + ks + 1) * 64 + lane];
        }
        const int cb = ks * 4 + hi;
        bf16x8 a0 = fa[rA0 * 24 + (cb ^ (rA0 & 7))];
        bf16x8 a1 = fa[rA1 * 24 + (cb ^ (rA1 & 7))];
        __builtin_amdgcn_s_setprio(1);
#pragma unroll
        for (int nf = 0; nf < 6; ++nf) {
            acc[0][nf] = __builtin_amdgcn_mfma_f32_16x16x32_bf16(a0, wf[nf], acc[0][nf], 0, 0, 0);
            acc[1][nf] = __builtin_amdgcn_mfma_f32_16x16x32_bf16(a1, wf[nf], acc[1][nf], 0, 0, 0);
        }
        __builtin_amdgcn_s_setprio(0);
        if (ks < 5) {
#pragma unroll
            for (int nf = 0; nf < 6; ++nf) wf[nf] = wfn[nf];
        }
    }

#pragma unroll
    for (int mt = 0; mt < 2; ++mt) {
#pragma unroll
        for (int nf = 0; nf < 6; ++nf) {
            f32x4 av = acc[mt][nf];
            const int nc = wn * 96 + nf * 16 + lm;
            const int mr = m0 + wm * 32 + mt * 16 + hi * 4;
            const float bv = bias[nc];
#pragma unroll
            for (int j = 0; j < 4; ++j)
                outb[(size_t)(mr + j) * 384 + nc] = (bf16)(av[j] + bv);
        }
    }
}

// ---------------- proj GEMM (R19-verified) ----------------
__global__ __launch_bounds__(512) void gemm_pj(
    const bf16* __restrict__ A, const bf16* __restrict__ Wpjp,
    const float* __restrict__ bias,
    float* __restrict__ outf,
    const float* __restrict__ resid, const float* __restrict__ ls,
    float2* __restrict__ pstats)
{
    __shared__ __align__(16) char ubuf[49920];   // phase1: sA 24576 B; phase2: lx [192][65] f32
    __shared__ float rs[512], rq[512];
    uint4* sA = (uint4*)ubuf;
    const int t = threadIdx.x;
    const int m0 = blockIdx.x * 64;
    const int lane = t & 63, wave = t >> 6;
    const int wm = wave >> 2, wn = wave & 3;
    const int lm = lane & 15, hi = lane >> 4;

    for (int i = t; i < 64 * 24; i += 512) {
        const int r = i / 24, ci = i % 24;
        sA[r * 24 + (ci ^ (r & 7))] = *(const uint4*)(A + (size_t)(m0 + r) * 192 + ci * 8);
    }
    __syncthreads();

    const bf16x8* fa = (const bf16x8*)sA;
    const bf16x8* fw = (const bf16x8*)Wpjp;
    const int rA0 = wm * 32 + lm, rA1 = rA0 + 16;

    f32x4 acc[2][3] = {};
    bf16x8 wf[3];
#pragma unroll
    for (int nf = 0; nf < 3; ++nf)
        wf[nf] = fw[((wn * 3 + nf) * 6 + 0) * 64 + lane];

#pragma unroll
    for (int ks = 0; ks < 6; ++ks) {
        bf16x8 wfn[3];
        if (ks < 5) {
#pragma unroll
            for (int nf = 0; nf < 3; ++nf)
                wfn[nf] = fw[((wn * 3 + nf) * 6 + ks + 1) * 64 + lane];
        }
        const int cb = ks * 4 + hi;
        bf16x8 a0 = fa[rA0 * 24 + (cb ^ (rA0 & 7))];
        bf16x8 a1 = fa[rA1 * 24 + (cb ^ (rA1 & 7))];
        __builtin_amdgcn_s_setprio(1);
#pragma unroll
        for (int nf = 0; nf < 3; ++nf) {
            acc[0][nf] = __builtin_amdgcn_mfma_f32_16x16x32_bf16(a0, wf[nf], acc[0][nf], 0, 0, 0);
            acc[1][nf] = __builtin_amdgcn_mfma_f32_16x16x32_bf16(a1, wf[nf], acc[1][nf], 0, 0, 0);
        }
        __builtin_amdgcn_s_setprio(0);
        if (ks < 5) {
#pragma unroll
            for (int nf = 0; nf < 3; ++nf) wf[nf] = wfn[nf];
        }
    }

    __syncthreads();
    float* lx = (float*)ubuf;            // [192][65]
    {
        const int bb0 = m0 >> 10, p0 = m0 & 1023;
        for (int i = t; i < 192 * 16; i += 512) {
            const int r = i >> 4, c4 = (i & 15) * 4;
            const float4 v = *(const float4*)(resid + ((size_t)bb0 * DIMC + r) * 1024 + p0 + c4);
            lx[r * 65 + c4 + 0] = v.x;
            lx[r * 65 + c4 + 1] = v.y;
            lx[r * 65 + c4 + 2] = v.z;
            lx[r * 65 + c4 + 3] = v.w;
        }
    }
    __syncthreads();

    float ps = 0.f, pq = 0.f;
#pragma unroll
    for (int mt = 0; mt < 2; ++mt) {
#pragma unroll
        for (int nf = 0; nf < 3; ++nf) {
            f32x4 av = acc[mt][nf];
            const int nc = wn * 48 + nf * 16 + lm;
            const int mr = m0 + wm * 32 + mt * 16 + hi * 4;
            const float bv = bias[nc];
#pragma unroll
            for (int j = 0; j < 4; ++j) {
                const int m = mr + j;
                const float v = av[j] + bv;
                const float xv = lx[nc * 65 + (m - m0)];
                const float x1 = xv + ls[nc] * v;
                outf[(size_t)m * DIMC + nc] = x1;
                ps += x1; pq += x1 * x1;
            }
        }
    }

    rs[t] = ps; rq[t] = pq; __syncthreads();
    for (int off = 256; off > 0; off >>= 1) {
        if (t < off) { rs[t] += rs[t + off]; rq[t] += rq[t + off]; }
        __syncthreads();
    }
    if (t == 0) {
        const int bb = blockIdx.x >> 4;
        const int slot = blockIdx.x & 15;
        pstats[bb * 16 + slot] = make_float2(rs[0], rq[0]);
    }
}

// ---------------- fused MLP: producer/consumer, 3 chunks per barrier ----------------
// R22 proved barrier-rendezvous dominance (13->7 barriers: 88->67 us). Extend to
// 12 chunks = 4 groups of 3 -> 5 barriers. sH[2][3] (48 KB; LDS 72 KB -> still
// 2 blocks/CU). Consumer reloads w2f[c3] IN-PLACE right after consuming chunk c3
// (live prefetch stays 12 frags = 48 VGPR -> no VGPR growth; R12 lesson).
// Race-free: consumer reads parity (pp-1)&1, producer writes parity pp&1;
// buffer reuse separated by two barriers.
__global__ __launch_bounds__(512) void mlp_k(
    const float* __restrict__ X1, const float2* __restrict__ part,
    const float* __restrict__ gw, const float* __restrict__ gb,
    const bf16* __restrict__ W1p, const float* __restrict__ b1,
    const bf16* __restrict__ W2p, const float* __restrict__ b2,
    const float* __restrict__ ls, float* __restrict__ out)
{
    __shared__ uint4 sA[64 * 24];           // 24 KB
    __shared__ bf16  sH[2][3][64 * 64];     // 48 KB: [group parity][chunk-in-group]

    const int t = threadIdx.x;
    const int m0 = blockIdx.x * 64;
    const int bb = m0 >> 10;
    const int lane = t & 63, wv = t >> 6;     // 0..7
    const int lm = lane & 15, hi = lane >> 4;
    const int lsw = lm & 7;

    const float2 mv = gn_mv_n(part, bb, 16);
    const bf16x8* fW1 = (const bf16x8*)W1p;
    const bf16x8* fW2 = (const bf16x8*)W2p;

    for (int cid = t; cid < 1536; cid += 512) {
        const int r = cid / 24, ci = cid % 24;
        const int c0 = ci * 8;
        const float* src = X1 + (size_t)(m0 + r) * 192 + c0;
        const float4 v0 = *(const float4*)(src);
        const float4 v1 = *(const float4*)(src + 4);
        const float4 w0 = *(const float4*)(gw + c0);
        const float4 w1 = *(const float4*)(gw + c0 + 4);
        const float4 g0 = *(const float4*)(gb + c0);
        const float4 g1 = *(const float4*)(gb + c0 + 4);
        bfu o;
        o.h[0] = (bf16)((v0.x - mv.x) * mv.y * w0.x + g0.x);
        o.h[1] = (bf16)((v0.y - mv.x) * mv.y * w0.y + g0.y);
        o.h[2] = (bf16)((v0.z - mv.x) * mv.y * w0.z + g0.z);
        o.h[3] = (bf16)((v0.w - mv.x) * mv.y * w0.w + g0.w);
        o.h[4] = (bf16)((v1.x - mv.x) * mv.y * w1.x + g1.x);
        o.h[5] = (bf16)((v1.y - mv.x) * mv.y * w1.y + g1.y);
        o.h[6] = (bf16)((v1.z - mv.x) * mv.y * w1.z + g1.z);
        o.h[7] = (bf16)((v1.w - mv.x) * mv.y * w1.w + g1.w);
        sA[r * 24 + (ci ^ (r & 7))] = o.u;
    }
    __syncthreads();

    const bf16x8* fa = (const bf16x8*)sA;

    if (wv < 4) {
        // ---------------- PRODUCER: hid cols pw*16+lm of each chunk ----------------
        const int pw = wv;
        bf16x8 w1f[6];
#pragma unroll
        for (int ks = 0; ks < 6; ++ks)
            w1f[ks] = fW1[(pw * 6 + ks) * 64 + lane];
        const int hcs = pw * 2 + (lm >> 3), hco = lm & 7;

        for (int pp = 0; pp <= 4; ++pp) {
            if (pp < 4) {
#pragma unroll
                for (int c3 = 0; c3 < 3; ++c3) {
                    const int jj = 3 * pp + c3;
                    f32x4 h[4];
#pragma unroll
                    for (int a = 0; a < 4; ++a) h[a] = (f32x4){0, 0, 0, 0};
                    __builtin_amdgcn_s_setprio(1);
#pragma unroll
                    for (int ks = 0; ks < 6; ++ks) {
                        const int cb = ks * 4 + hi;
                        bf16x8 a0 = fa[(lm)      * 24 + (cb ^ lsw)];
                        bf16x8 a1 = fa[(16 + lm) * 24 + (cb ^ lsw)];
                        bf16x8 a2 = fa[(32 + lm) * 24 + (cb ^ lsw)];
                        bf16x8 a3 = fa[(48 + lm) * 24 + (cb ^ lsw)];
                        h[0] = __builtin_amdgcn_mfma_f32_16x16x32_bf16(a0, w1f[ks], h[0], 0, 0, 0);
                        h[1] = __builtin_amdgcn_mfma_f32_16x16x32_bf16(a1, w1f[ks], h[1], 0, 0, 0);
                        h[2] = __builtin_amdgcn_mfma_f32_16x16x32_bf16(a2, w1f[ks], h[2], 0, 0, 0);
                        h[3] = __builtin_amdgcn_mfma_f32_16x16x32_bf16(a3, w1f[ks], h[3], 0, 0, 0);
                    }
                    __builtin_amdgcn_s_setprio(0);

                    if (jj < 11) {
#pragma unroll
                        for (int ks = 0; ks < 6; ++ks)
                            w1f[ks] = fW1[(((jj + 1) * 4 + pw) * 6 + ks) * 64 + lane];
                    }

                    bf16* sh = sH[pp & 1][c3];
                    const float b1v = b1[jj * 64 + pw * 16 + lm];
#pragma unroll
                    for (int mfr = 0; mfr < 4; ++mfr) {
#pragma unroll
                        for (int q = 0; q < 4; ++q) {
                            const int m = mfr * 16 + hi * 4 + q;
                            const float vv = h[mfr][q] + b1v;
                            const float g = vv * __builtin_amdgcn_rcpf(1.f + __expf(-1.702f * vv));
                            sh[m * 64 + ((hcs ^ (m & 7)) << 3) + hco] = (bf16)g;
                        }
                    }
                }
            }
            __syncthreads();
        }
    } else {
        // ---------------- CONSUMER: out cols cw*48 .. +48 ----------------
        const int cw = wv - 4;
        f32x4 oa[4][3];
#pragma unroll
        for (int a = 0; a < 4; ++a)
#pragma unroll
            for (int bq = 0; bq < 3; ++bq) oa[a][bq] = (f32x4){0, 0, 0, 0};

        bf16x8 w2f[3][3][2];   // [chunk-in-group][bqi][ks]; holds ONE group, reloaded in place
#pragma unroll
        for (int c3 = 0; c3 < 3; ++c3)
#pragma unroll
            for (int bqi = 0; bqi < 3; ++bqi)
#pragma unroll
                for (int ks = 0; ks < 2; ++ks)
                    w2f[c3][bqi][ks] = fW2[(((c3 * 4 + cw) * 3 + bqi) * 2 + ks) * 64 + lane];

        for (int pp = 0; pp <= 4; ++pp) {
            if (pp >= 1) {
#pragma unroll
                for (int c3 = 0; c3 < 3; ++c3) {
                    const bf16x8* fh = (const bf16x8*)sH[(pp - 1) & 1][c3];
                    __builtin_amdgcn_s_setprio(1);
#pragma unroll
                    for (int ks = 0; ks < 2; ++ks) {
                        const int cc = ks * 4 + hi;
#pragma unroll
                        for (int mfr = 0; mfr < 4; ++mfr) {
                            bf16x8 ah = fh[(mfr * 16 + lm) * 8 + (cc ^ lsw)];
                            oa[mfr][0] = __builtin_amdgcn_mfma_f32_16x16x32_bf16(ah, w2f[c3][0][ks], oa[mfr][0], 0, 0, 0);
                            oa[mfr][1] = __builtin_amdgcn_mfma_f32_16x16x32_bf16(ah, w2f[c3][1][ks], oa[mfr][1], 0, 0, 0);
                            oa[mfr][2] = __builtin_amdgcn_mfma_f32_16x16x32_bf16(ah, w2f[c3][2][ks], oa[mfr][2], 0, 0, 0);
                        }
                    }
                    __builtin_amdgcn_s_setprio(0);

                    // reload this slot with group pp's chunk (3*pp+c3), consumed next iter
                    if (pp < 4) {
#pragma unroll
                        for (int bqi = 0; bqi < 3; ++bqi)
#pragma unroll
                            for (int ks = 0; ks < 2; ++ks)
                                w2f[c3][bqi][ks] = fW2[((((3 * pp + c3) * 4 + cw) * 3 + bqi) * 2 + ks) * 64 + lane];
                    }
                }
            }
            __syncthreads();
        }

        // epilogue (consumers only): out(NCHW) = X1 + ls2 * (acc + b2)
#pragma unroll
        for (int mfr = 0; mfr < 4; ++mfr) {
#pragma unroll
            for (int bqi = 0; bqi < 3; ++bqi) {
                f32x4 av = oa[mfr][bqi];
                const int nc = cw * 48 + bqi * 16 + lm;
                const int mr = mfr * 16 + hi * 4;
                const float b2v = b2[nc], lsv = ls[nc];
                const float* xp = X1 + (size_t)(m0 + mr) * 192 + nc;
                float4 ov;
                ov.x = xp[0]   + lsv * (av[0] + b2v);
                ov.y = xp[192] + lsv * (av[1] + b2v);
                ov.z = xp[384] + lsv * (av[2] + b2v);
                ov.w = xp[576] + lsv * (av[3] + b2v);
                *(float4*)(out + ((size_t)bb * DIMC + nc) * 1024 + (m0 & 1023) + mr) = ov;
            }
        }
    }
}

// ---------------- cluster (R15-verified) ----------------
__global__ __launch_bounds__(256) void cluster_k(
    const bf16* __restrict__ FV, bf16* __restrict__ Y,
    const float* __restrict__ alpha_p, const float* __restrict__ beta_p)
{
    __shared__ __align__(16) char u_raw[25600];
    __shared__ float cf[4][24], cv[4][24];
    __shared__ float partial[8][4][24];
    __shared__ int   cntp[4][4];
    __shared__ float aggL[4][24];
    __shared__ int   bestL[256];

    const int g = blockIdx.x;
    const int bb = g >> 5, e = (g >> 2) & 7, f1 = (g >> 1) & 1, f2 = g & 1;
    const int t = threadIdx.x;
    const int wi = t >> 4, hj = t & 15;
    const int p = (f1 * 16 + wi) * 32 + (f2 * 16 + hj);
    const size_t tok = (size_t)bb * 1024 + p;

    const bf16x8* src = (const bf16x8*)(FV + tok * 384);
    bf16x8 hf0 = src[e * 3 + 0], hf1 = src[e * 3 + 1], hf2 = src[e * 3 + 2];
    bf16x8 hv0 = src[24 + e * 3 + 0], hv1 = src[24 + e * 3 + 1], hv2 = src[24 + e * 3 + 2];

    bf16* lfv = (bf16*)u_raw;                    // [256][48]
    {
        bf16x8* row = (bf16x8*)(lfv + t * 48);
        row[0] = hf0; row[1] = hf1; row[2] = hf2;
        row[3] = hv0; row[4] = hv1; row[5] = hv2;
    }
    float freg[24];
#pragma unroll
    for (int j = 0; j < 8; ++j) {
        freg[j] = (float)hf0[j]; freg[8 + j] = (float)hf1[j]; freg[16 + j] = (float)hf2[j];
    }
    __syncthreads();

    if (t < 192) {
        const int team = t / 96;
        const int idx = t % 96;
        const int m = idx / 24, c = idx % 24;
        const int pw = m >> 1, ph = m & 1;
        float s = 0.f;
        for (int a = 0; a < 8; ++a) {
            const int nb = (pw * 8 + a) * 16 + ph * 8;
#pragma unroll
            for (int bj = 0; bj < 8; ++bj)
                s += (float)lfv[(nb + bj) * 48 + team * 24 + c];
        }
        if (team) cv[m][c] = s * (1.f / 64.f);
        else      cf[m][c] = s * (1.f / 64.f);
    }
    __syncthreads();

    float nrm = 0.f;
#pragma unroll
    for (int c = 0; c < 24; ++c) nrm += freg[c] * freg[c];
    const float invf = 1.f / fmaxf(sqrtf(nrm), 1e-12f);
    const float alpha = alpha_p[0], beta = beta_p[0];
    float bestv = -1.f; int best = 0;
#pragma unroll
    for (int m = 0; m < 4; ++m) {
        float d = 0.f, cs = 0.f;
#pragma unroll
        for (int c = 0; c < 24; ++c) {
            const float cfv = cf[m][c];
            d += cfv * freg[c];
            cs += cfv * cfv;
        }
        const float z = beta + alpha * d * (1.f / fmaxf(sqrtf(cs), 1e-12f)) * invf;
        const float sim = 1.f / (1.f + expf(-z));
        if (sim > bestv) { bestv = sim; best = m; }
    }

    {
        const unsigned long long q0 = __ballot(best == 0);
        const unsigned long long q1 = __ballot(best == 1);
        const unsigned long long q2 = __ballot(best == 2);
        const unsigned long long q3 = __ballot(best == 3);
        if ((t & 63) == 0) {
            const int w = t >> 6;
            cntp[w][0] = __popcll(q0); cntp[w][1] = __popcll(q1);
            cntp[w][2] = __popcll(q2); cntp[w][3] = __popcll(q3);
        }
    }

    float (*pvL)[25] = (float (*)[25])u_raw;
#pragma unroll
    for (int j = 0; j < 8; ++j) {
        pvL[t][j]      = bestv * (float)hv0[j];
        pvL[t][8 + j]  = bestv * (float)hv1[j];
        pvL[t][16 + j] = bestv * (float)hv2[j];
    }
    bestL[t] = best;
    __syncthreads();

    if (t < 192) {
        const int seg = t / 24, c = t % 24;
        float a0 = 0.f, a1 = 0.f, a2 = 0.f, a3 = 0.f;
        const int nb = seg * 32;
        for (int i = 0; i < 32; ++i) {
            const int n = nb + i;
            const int bm = bestL[n];
            const float x = pvL[n][c];
            a0 += (bm == 0) ? x : 0.f;
            a1 += (bm == 1) ? x : 0.f;
            a2 += (bm == 2) ? x : 0.f;
            a3 += (bm == 3) ? x : 0.f;
        }
        partial[seg][0][c] = a0; partial[seg][1][c] = a1;
        partial[seg][2][c] = a2; partial[seg][3][c] = a3;
    }
    __syncthreads();

    if (t < 96) {
        const int m = t / 24, c = t % 24;
        float s = 0.f;
#pragma unroll
        for (int seg = 0; seg < 8; ++seg) s += partial[seg][m][c];
        const int cnt = cntp[0][m] + cntp[1][m] + cntp[2][m] + cntp[3][m];
        aggL[m][c] = (s + cv[m][c]) / ((float)cnt + 1.f);
    }
    __syncthreads();

    const float sv = bestv; const int bm = best;
    bf16x8 z0, z1, z2;
#pragma unroll
    for (int j = 0; j < 8; ++j) {
        z0[j] = (bf16)(aggL[bm][j] * sv);
        z1[j] = (bf16)(aggL[bm][8 + j] * sv);
        z2[j] = (bf16)(aggL[bm][16 + j] * sv);
    }
    bf16x8* dst = (bf16x8*)(Y + tok * DIMC + e * 24);
    dst[0] = z0; dst[1] = z1; dst[2] = z2;
}

// ---------------- launch ----------------
extern "C" void kernel_launch(void* const* d_in, const int* in_sizes, int n_in,
                              void* d_out, int out_size, void* d_ws, size_t ws_size,
                              hipStream_t stream)
{
    (void)in_sizes; (void)n_in; (void)out_size; (void)ws_size;
    const float* x      = (const float*)d_in[0];
    const float* gn1_w  = (const float*)d_in[1];
    const float* gn1_b  = (const float*)d_in[2];
    const float* f_w    = (const float*)d_in[3];
    const float* f_b    = (const float*)d_in[4];
    const float* v_w    = (const float*)d_in[5];
    const float* v_b    = (const float*)d_in[6];
    const float* proj_w = (const float*)d_in[7];
    const float* proj_b = (const float*)d_in[8];
    const float* alpha  = (const float*)d_in[9];
    const float* beta   = (const float*)d_in[10];
    const float* ls1    = (const float*)d_in[11];
    const float* gn2_w  = (const float*)d_in[12];
    const float* gn2_b  = (const float*)d_in[13];
    const float* fc1_w  = (const float*)d_in[14];
    const float* fc1_b  = (const float*)d_in[15];
    const float* fc2_w  = (const float*)d_in[16];
    const float* fc2_b  = (const float*)d_in[17];
    const float* ls2    = (const float*)d_in[18];

    char* ws = (char*)d_ws;
    float2* part1 = (float2*)(ws + OFF_PART1);
    float2* part2 = (float2*)(ws + OFF_PART2);
    float* biasfv = (float*)(ws + OFF_BIASFV);
    bf16* Wfvp  = (bf16*)(ws + OFF_WFV);
    bf16* Wpjp  = (bf16*)(ws + OFF_WPJ);
    bf16* W1p   = (bf16*)(ws + OFF_W1P);
    bf16* W2p   = (bf16*)(ws + OFF_W2P);
    bf16* FVb   = (bf16*)(ws + OFF_FV);
    bf16* Yb    = (bf16*)(ws + OFF_Y);
    float* X1   = (float*)(ws + OFF_X1);
    float* out  = (float*)d_out;

    prep_stats<<<1600, 256, 0, stream>>>(f_w, v_w, proj_w, fc1_w, fc2_w, f_b, v_b,
                                         Wfvp, Wpjp, W1p, W2p, biasfv, x, part1);
    gemm_fv3<<<1024, 512, 0, stream>>>(x, part1, gn1_w, gn1_b, Wfvp, biasfv, FVb);
    cluster_k<<<2048, 256, 0, stream>>>(FVb, Yb, alpha, beta);
    gemm_pj<<<1024, 512, 0, stream>>>(Yb, Wpjp, proj_b, X1, x, ls1, part2);
    mlp_k<<<1024, 512, 0, stream>>>(X1, part2, gn2_w, gn2_b,
                                    W1p, fc1_b, W2p, fc2_b, ls2, out);
}

// Round 24
// 148.606 us; speedup vs baseline: 1.1290x; 1.1290x over previous
//
#include <hip/hip_runtime.h>
#include <math.h>

typedef __bf16 bf16;
typedef __bf16 bf16x8 __attribute__((ext_vector_type(8)));
typedef __bf16 bf16x4 __attribute__((ext_vector_type(4)));
typedef float  f32x4  __attribute__((ext_vector_type(4)));

union bfu { bf16x8 h; uint4 u; };

#define NSAMP 64
#define DIMC 192
#define SAMP_ELEMS 196608
#define M_TOK 65536

// ---- workspace layout (bytes) ----
constexpr size_t OFF_PART1  = 0;
constexpr size_t OFF_PART2  = 8192;
constexpr size_t OFF_BIASFV = 40960;
constexpr size_t OFF_WFV    = 43008;                // fragment-packed Wfv (147456 B)
constexpr size_t OFF_WPJ    = OFF_WFV + 147456;     // fragment-packed Wproj (73728 B)
constexpr size_t OFF_W1P    = OFF_WPJ + 73728;      // fragment-packed W1 (294912 B)
constexpr size_t OFF_W2P    = OFF_W1P + 294912;     // fragment-packed W2 (294912 B)
constexpr size_t OFF_R      = 1048576;
constexpr size_t OFF_FV     = OFF_R;
constexpr size_t OFF_Y      = OFF_R + 50331648;
constexpr size_t OFF_X1     = OFF_R + 100663296;

// ---------------- fused weight-prep + GN1 stats ----------------
// Blocks [0,576): weight prep (incl. Wpjp). Blocks [576,1600): GN1 stats over x.
__global__ __launch_bounds__(256) void prep_stats(
    const float* __restrict__ f_w, const float* __restrict__ v_w,
    const float* __restrict__ proj_w,
    const float* __restrict__ fc1_w, const float* __restrict__ fc2_w,
    const float* __restrict__ f_b, const float* __restrict__ v_b,
    bf16* __restrict__ Wfvp, bf16* __restrict__ Wpjp,
    bf16* __restrict__ W1p, bf16* __restrict__ W2p,
    float* __restrict__ biasfv,
    const float* __restrict__ X, float2* __restrict__ part)
{
    if (blockIdx.x >= 576) {
        const int blk = blockIdx.x - 576;
        const int b = blk >> 4, seg = blk & 15;
        const float4* p = (const float4*)(X + (size_t)b * SAMP_ELEMS + (size_t)seg * 12288);
        float s = 0.f, q = 0.f;
        for (int i = threadIdx.x; i < 3072; i += 256) {
            float4 v = p[i];
            s += v.x + v.y + v.z + v.w;
            q += v.x * v.x + v.y * v.y + v.z * v.z + v.w * v.w;
        }
        __shared__ float bs[256], bq[256];
        const int t = threadIdx.x;
        bs[t] = s; bq[t] = q; __syncthreads();
        for (int off = 128; off > 0; off >>= 1) {
            if (t < off) { bs[t] += bs[t + off]; bq[t] += bq[t + off]; }
            __syncthreads();
        }
        if (t == 0) part[b * 16 + seg] = make_float2(bs[0], bq[0]);
        return;
    }

    const int i = blockIdx.x * 256 + threadIdx.x;
    if (i < 73728) {
        const int e = i & 7, l = (i >> 3) & 63, f = i >> 9;
        const int ks = f % 6, wnf = f / 6;
        const int o = wnf * 16 + (l & 15);
        const int k = ks * 32 + (l >> 4) * 8 + e;
        Wfvp[i] = (bf16)(o < 192 ? f_w[o * 192 + k] : v_w[(o - 192) * 192 + k]);
    }
    if (i < 36864) {
        const int e = i & 7, l = (i >> 3) & 63, f = i >> 9;
        const int ks = f % 6, wnf = f / 6;
        const int o = wnf * 16 + (l & 15);
        const int k = ks * 32 + (l >> 4) * 8 + e;
        Wpjp[i] = (bf16)proj_w[o * 192 + k];
    }
    if (i < 147456) {
        const int e = i & 7, l = (i >> 3) & 63, f = i >> 9;
        const int ks = f % 6, pwj = f / 6;
        const int o = (pwj >> 2) * 64 + (pwj & 3) * 16 + (l & 15);
        const int k = ks * 32 + (l >> 4) * 8 + e;
        W1p[i] = (bf16)fc1_w[k * 768 + o];
    }
    if (i < 147456) {
        const int e = i & 7, l = (i >> 3) & 63, g = i >> 9;
        const int ks = g & 1, g1 = g >> 1;
        const int bqi = g1 % 3, jcw = g1 / 3;
        const int o = (jcw & 3) * 48 + bqi * 16 + (l & 15);
        const int k = (jcw >> 2) * 64 + ks * 32 + (l >> 4) * 8 + e;
        W2p[i] = (bf16)fc2_w[k * 192 + o];
    }
    if (i < 384) biasfv[i] = i < 192 ? f_b[i] : v_b[i - 192];
}

__device__ inline float2 gn_mv_n(const float2* __restrict__ part, int b, int n)
{
    float s = 0.f, q = 0.f;
    for (int i = 0; i < n; ++i) { float2 v = part[b * n + i]; s += v.x; q += v.y; }
    const float mean = s * (1.f / (float)SAMP_ELEMS);
    const float var = q * (1.f / (float)SAMP_ELEMS) - mean * mean;
    float2 r; r.x = mean; r.y = rsqrtf(var + 1e-5f);
    return r;
}

// ---------------- fused GN1 + f/v conv GEMM (R20-verified) ----------------
__global__ __launch_bounds__(512) void gemm_fv3(
    const float* __restrict__ X, const float2* __restrict__ part,
    const float* __restrict__ gw, const float* __restrict__ gb,
    const bf16* __restrict__ Wfvp, const float* __restrict__ bias,
    bf16* __restrict__ outb)
{
    __shared__ uint4 sA[64 * 24];
    const int t = threadIdx.x;
    const int m0 = blockIdx.x * 64;
    const int bb = m0 >> 10, p0 = m0 & 1023;
    const int lane = t & 63, wave = t >> 6;
    const int wm = wave >> 2, wn = wave & 3;
    const int lm = lane & 15, hi = lane >> 4;
    const float2 mv = gn_mv_n(part, bb, 16);

    bf16* sab = (bf16*)sA;
    for (int i = t; i < 3072; i += 512) {
        const int c = i >> 4, pq = i & 15;
        const float4 v = *(const float4*)(X + ((size_t)bb * DIMC + c) * 1024 + p0 + pq * 4);
        const float scale = gw[c] * mv.y;
        const float shift = gb[c] - mv.x * scale;
        const int ci = c >> 3, co = c & 7;
#pragma unroll
        for (int j = 0; j < 4; ++j) {
            const int r = pq * 4 + j;
            sab[(r * 24 + (ci ^ (r & 7))) * 8 + co] = (bf16)((&v.x)[j] * scale + shift);
        }
    }
    __syncthreads();

    const bf16x8* fa = (const bf16x8*)sA;
    const bf16x8* fw = (const bf16x8*)Wfvp;
    const int rA0 = wm * 32 + lm, rA1 = rA0 + 16;

    f32x4 acc[2][6] = {};
    bf16x8 wf[6];
#pragma unroll
    for (int nf = 0; nf < 6; ++nf)
        wf[nf] = fw[((wn * 6 + nf) * 6 + 0) * 64 + lane];

#pragma unroll
    for (int ks = 0; ks < 6; ++ks) {
        bf16x8 wfn[6];
        if (ks < 5) {
#pragma unroll
            for (int nf = 0; nf < 6; ++nf)
                wfn[nf] = fw[((wn * 6 + nf) * 6 + ks + 1) * 64 + lane];
        }
        const int cb = ks * 4 + hi;
        bf16x8 a0 = fa[rA0 * 24 + (cb ^ (rA0 & 7))];
        bf16x8 a1 = fa[rA1 * 24 + (cb ^ (rA1 & 7))];
        __builtin_amdgcn_s_setprio(1);
#pragma unroll
        for (int nf = 0; nf < 6; ++nf) {
            acc[0][nf] = __builtin_amdgcn_mfma_f32_16x16x32_bf16(a0, wf[nf], acc[0][nf], 0, 0, 0);
            acc[1][nf] = __builtin_amdgcn_mfma_f32_16x16x32_bf16(a1, wf[nf], acc[1][nf], 0, 0, 0);
        }
        __builtin_amdgcn_s_setprio(0);
        if (ks < 5) {
#pragma unroll
            for (int nf = 0; nf < 6; ++nf) wf[nf] = wfn[nf];
        }
    }

#pragma unroll
    for (int mt = 0; mt < 2; ++mt) {
#pragma unroll
        for (int nf = 0; nf < 6; ++nf) {
            f32x4 av = acc[mt][nf];
            const int nc = wn * 96 + nf * 16 + lm;
            const int mr = m0 + wm * 32 + mt * 16 + hi * 4;
            const float bv = bias[nc];
#pragma unroll
            for (int j = 0; j < 4; ++j)
                outb[(size_t)(mr + j) * 384 + nc] = (bf16)(av[j] + bv);
        }
    }
}

// ---------------- proj GEMM (R19-verified) ----------------
__global__ __launch_bounds__(512) void gemm_pj(
    const bf16* __restrict__ A, const bf16* __restrict__ Wpjp,
    const float* __restrict__ bias,
    float* __restrict__ outf,
    const float* __restrict__ resid, const float* __restrict__ ls,
    float2* __restrict__ pstats)
{
    __shared__ __align__(16) char ubuf[49920];   // phase1: sA 24576 B; phase2: lx [192][65] f32
    __shared__ float rs[512], rq[512];
    uint4* sA = (uint4*)ubuf;
    const int t = threadIdx.x;
    const int m0 = blockIdx.x * 64;
    const int lane = t & 63, wave = t >> 6;
    const int wm = wave >> 2, wn = wave & 3;
    const int lm = lane & 15, hi = lane >> 4;

    for (int i = t; i < 64 * 24; i += 512) {
        const int r = i / 24, ci = i % 24;
        sA[r * 24 + (ci ^ (r & 7))] = *(const uint4*)(A + (size_t)(m0 + r) * 192 + ci * 8);
    }
    __syncthreads();

    const bf16x8* fa = (const bf16x8*)sA;
    const bf16x8* fw = (const bf16x8*)Wpjp;
    const int rA0 = wm * 32 + lm, rA1 = rA0 + 16;

    f32x4 acc[2][3] = {};
    bf16x8 wf[3];
#pragma unroll
    for (int nf = 0; nf < 3; ++nf)
        wf[nf] = fw[((wn * 3 + nf) * 6 + 0) * 64 + lane];

#pragma unroll
    for (int ks = 0; ks < 6; ++ks) {
        bf16x8 wfn[3];
        if (ks < 5) {
#pragma unroll
            for (int nf = 0; nf < 3; ++nf)
                wfn[nf] = fw[((wn * 3 + nf) * 6 + ks + 1) * 64 + lane];
        }
        const int cb = ks * 4 + hi;
        bf16x8 a0 = fa[rA0 * 24 + (cb ^ (rA0 & 7))];
        bf16x8 a1 = fa[rA1 * 24 + (cb ^ (rA1 & 7))];
        __builtin_amdgcn_s_setprio(1);
#pragma unroll
        for (int nf = 0; nf < 3; ++nf) {
            acc[0][nf] = __builtin_amdgcn_mfma_f32_16x16x32_bf16(a0, wf[nf], acc[0][nf], 0, 0, 0);
            acc[1][nf] = __builtin_amdgcn_mfma_f32_16x16x32_bf16(a1, wf[nf], acc[1][nf], 0, 0, 0);
        }
        __builtin_amdgcn_s_setprio(0);
        if (ks < 5) {
#pragma unroll
            for (int nf = 0; nf < 3; ++nf) wf[nf] = wfn[nf];
        }
    }

    __syncthreads();
    float* lx = (float*)ubuf;            // [192][65]
    {
        const int bb0 = m0 >> 10, p0 = m0 & 1023;
        for (int i = t; i < 192 * 16; i += 512) {
            const int r = i >> 4, c4 = (i & 15) * 4;
            const float4 v = *(const float4*)(resid + ((size_t)bb0 * DIMC + r) * 1024 + p0 + c4);
            lx[r * 65 + c4 + 0] = v.x;
            lx[r * 65 + c4 + 1] = v.y;
            lx[r * 65 + c4 + 2] = v.z;
            lx[r * 65 + c4 + 3] = v.w;
        }
    }
    __syncthreads();

    float ps = 0.f, pq = 0.f;
#pragma unroll
    for (int mt = 0; mt < 2; ++mt) {
#pragma unroll
        for (int nf = 0; nf < 3; ++nf) {
            f32x4 av = acc[mt][nf];
            const int nc = wn * 48 + nf * 16 + lm;
            const int mr = m0 + wm * 32 + mt * 16 + hi * 4;
            const float bv = bias[nc];
#pragma unroll
            for (int j = 0; j < 4; ++j) {
                const int m = mr + j;
                const float v = av[j] + bv;
                const float xv = lx[nc * 65 + (m - m0)];
                const float x1 = xv + ls[nc] * v;
                outf[(size_t)m * DIMC + nc] = x1;
                ps += x1; pq += x1 * x1;
            }
        }
    }

    rs[t] = ps; rq[t] = pq; __syncthreads();
    for (int off = 256; off > 0; off >>= 1) {
        if (t < off) { rs[t] += rs[t + off]; rq[t] += rq[t + off]; }
        __syncthreads();
    }
    if (t == 0) {
        const int bb = blockIdx.x >> 4;
        const int slot = blockIdx.x & 15;
        pstats[bb * 16 + slot] = make_float2(rs[0], rq[0]);
    }
}

// ---------------- fused MLP: producer/consumer, 2 chunks per barrier (R22-verified, 67 us) ----------------
__global__ __launch_bounds__(512) void mlp_k(
    const float* __restrict__ X1, const float2* __restrict__ part,
    const float* __restrict__ gw, const float* __restrict__ gb,
    const bf16* __restrict__ W1p, const float* __restrict__ b1,
    const bf16* __restrict__ W2p, const float* __restrict__ b2,
    const float* __restrict__ ls, float* __restrict__ out)
{
    __shared__ uint4 sA[64 * 24];           // 24 KB
    __shared__ bf16  sH[2][2][64 * 64];     // 32 KB: [pair parity][chunk-in-pair]

    const int t = threadIdx.x;
    const int m0 = blockIdx.x * 64;
    const int bb = m0 >> 10;
    const int lane = t & 63, wv = t >> 6;     // 0..7
    const int lm = lane & 15, hi = lane >> 4;
    const int lsw = lm & 7;

    const float2 mv = gn_mv_n(part, bb, 16);
    const bf16x8* fW1 = (const bf16x8*)W1p;
    const bf16x8* fW2 = (const bf16x8*)W2p;

    for (int cid = t; cid < 1536; cid += 512) {
        const int r = cid / 24, ci = cid % 24;
        const int c0 = ci * 8;
        const float* src = X1 + (size_t)(m0 + r) * 192 + c0;
        const float4 v0 = *(const float4*)(src);
        const float4 v1 = *(const float4*)(src + 4);
        const float4 w0 = *(const float4*)(gw + c0);
        const float4 w1 = *(const float4*)(gw + c0 + 4);
        const float4 g0 = *(const float4*)(gb + c0);
        const float4 g1 = *(const float4*)(gb + c0 + 4);
        bfu o;
        o.h[0] = (bf16)((v0.x - mv.x) * mv.y * w0.x + g0.x);
        o.h[1] = (bf16)((v0.y - mv.x) * mv.y * w0.y + g0.y);
        o.h[2] = (bf16)((v0.z - mv.x) * mv.y * w0.z + g0.z);
        o.h[3] = (bf16)((v0.w - mv.x) * mv.y * w0.w + g0.w);
        o.h[4] = (bf16)((v1.x - mv.x) * mv.y * w1.x + g1.x);
        o.h[5] = (bf16)((v1.y - mv.x) * mv.y * w1.y + g1.y);
        o.h[6] = (bf16)((v1.z - mv.x) * mv.y * w1.z + g1.z);
        o.h[7] = (bf16)((v1.w - mv.x) * mv.y * w1.w + g1.w);
        sA[r * 24 + (ci ^ (r & 7))] = o.u;
    }
    __syncthreads();

    const bf16x8* fa = (const bf16x8*)sA;

    if (wv < 4) {
        // ---------------- PRODUCER: hid cols pw*16+lm of each chunk ----------------
        const int pw = wv;
        bf16x8 w1f[6];
#pragma unroll
        for (int ks = 0; ks < 6; ++ks)
            w1f[ks] = fW1[(pw * 6 + ks) * 64 + lane];
        const int hcs = pw * 2 + (lm >> 3), hco = lm & 7;

        for (int pp = 0; pp <= 6; ++pp) {
            if (pp < 6) {
#pragma unroll
                for (int c2 = 0; c2 < 2; ++c2) {
                    const int jj = 2 * pp + c2;
                    f32x4 h[4];
#pragma unroll
                    for (int a = 0; a < 4; ++a) h[a] = (f32x4){0, 0, 0, 0};
                    __builtin_amdgcn_s_setprio(1);
#pragma unroll
                    for (int ks = 0; ks < 6; ++ks) {
                        const int cb = ks * 4 + hi;
                        bf16x8 a0 = fa[(lm)      * 24 + (cb ^ lsw)];
                        bf16x8 a1 = fa[(16 + lm) * 24 + (cb ^ lsw)];
                        bf16x8 a2 = fa[(32 + lm) * 24 + (cb ^ lsw)];
                        bf16x8 a3 = fa[(48 + lm) * 24 + (cb ^ lsw)];
                        h[0] = __builtin_amdgcn_mfma_f32_16x16x32_bf16(a0, w1f[ks], h[0], 0, 0, 0);
                        h[1] = __builtin_amdgcn_mfma_f32_16x16x32_bf16(a1, w1f[ks], h[1], 0, 0, 0);
                        h[2] = __builtin_amdgcn_mfma_f32_16x16x32_bf16(a2, w1f[ks], h[2], 0, 0, 0);
                        h[3] = __builtin_amdgcn_mfma_f32_16x16x32_bf16(a3, w1f[ks], h[3], 0, 0, 0);
                    }
                    __builtin_amdgcn_s_setprio(0);

                    if (jj < 11) {
#pragma unroll
                        for (int ks = 0; ks < 6; ++ks)
                            w1f[ks] = fW1[(((jj + 1) * 4 + pw) * 6 + ks) * 64 + lane];
                    }

                    bf16* sh = sH[pp & 1][c2];
                    const float b1v = b1[jj * 64 + pw * 16 + lm];
#pragma unroll
                    for (int mfr = 0; mfr < 4; ++mfr) {
#pragma unroll
                        for (int q = 0; q < 4; ++q) {
                            const int m = mfr * 16 + hi * 4 + q;
                            const float vv = h[mfr][q] + b1v;
                            const float g = vv * __builtin_amdgcn_rcpf(1.f + __expf(-1.702f * vv));
                            sh[m * 64 + ((hcs ^ (m & 7)) << 3) + hco] = (bf16)g;
                        }
                    }
                }
            }
            __syncthreads();
        }
    } else {
        // ---------------- CONSUMER: out cols cw*48 .. +48 ----------------
        const int cw = wv - 4;
        f32x4 oa[4][3];
#pragma unroll
        for (int a = 0; a < 4; ++a)
#pragma unroll
            for (int bq = 0; bq < 3; ++bq) oa[a][bq] = (f32x4){0, 0, 0, 0};

        bf16x8 w2f[2][3][2];   // [chunk-in-pair][bqi][ks], prefetch chunks 0,1
#pragma unroll
        for (int c2 = 0; c2 < 2; ++c2)
#pragma unroll
            for (int bqi = 0; bqi < 3; ++bqi)
#pragma unroll
                for (int ks = 0; ks < 2; ++ks)
                    w2f[c2][bqi][ks] = fW2[(((c2 * 4 + cw) * 3 + bqi) * 2 + ks) * 64 + lane];

        for (int pp = 0; pp <= 6; ++pp) {
            if (pp >= 1) {
#pragma unroll
                for (int c2 = 0; c2 < 2; ++c2) {
                    const bf16x8* fh = (const bf16x8*)sH[(pp - 1) & 1][c2];
                    __builtin_amdgcn_s_setprio(1);
#pragma unroll
                    for (int ks = 0; ks < 2; ++ks) {
                        const int cc = ks * 4 + hi;
#pragma unroll
                        for (int mfr = 0; mfr < 4; ++mfr) {
                            bf16x8 ah = fh[(mfr * 16 + lm) * 8 + (cc ^ lsw)];
                            oa[mfr][0] = __builtin_amdgcn_mfma_f32_16x16x32_bf16(ah, w2f[c2][0][ks], oa[mfr][0], 0, 0, 0);
                            oa[mfr][1] = __builtin_amdgcn_mfma_f32_16x16x32_bf16(ah, w2f[c2][1][ks], oa[mfr][1], 0, 0, 0);
                            oa[mfr][2] = __builtin_amdgcn_mfma_f32_16x16x32_bf16(ah, w2f[c2][2][ks], oa[mfr][2], 0, 0, 0);
                        }
                    }
                    __builtin_amdgcn_s_setprio(0);
                }

                // prefetch next pair's W2 fragments (chunks 2pp, 2pp+1)
                if (pp < 6) {
#pragma unroll
                    for (int c2 = 0; c2 < 2; ++c2)
#pragma unroll
                        for (int bqi = 0; bqi < 3; ++bqi)
#pragma unroll
                            for (int ks = 0; ks < 2; ++ks)
                                w2f[c2][bqi][ks] = fW2[((((2 * pp + c2) * 4 + cw) * 3 + bqi) * 2 + ks) * 64 + lane];
                }
            }
            __syncthreads();
        }

        // epilogue (consumers only): out(NCHW) = X1 + ls2 * (acc + b2)
#pragma unroll
        for (int mfr = 0; mfr < 4; ++mfr) {
#pragma unroll
            for (int bqi = 0; bqi < 3; ++bqi) {
                f32x4 av = oa[mfr][bqi];
                const int nc = cw * 48 + bqi * 16 + lm;
                const int mr = mfr * 16 + hi * 4;
                const float b2v = b2[nc], lsv = ls[nc];
                const float* xp = X1 + (size_t)(m0 + mr) * 192 + nc;
                float4 ov;
                ov.x = xp[0]   + lsv * (av[0] + b2v);
                ov.y = xp[192] + lsv * (av[1] + b2v);
                ov.z = xp[384] + lsv * (av[2] + b2v);
                ov.w = xp[576] + lsv * (av[3] + b2v);
                *(float4*)(out + ((size_t)bb * DIMC + nc) * 1024 + (m0 & 1023) + mr) = ov;
            }
        }
    }
}

// ---------------- cluster (R15-verified) ----------------
__global__ __launch_bounds__(256) void cluster_k(
    const bf16* __restrict__ FV, bf16* __restrict__ Y,
    const float* __restrict__ alpha_p, const float* __restrict__ beta_p)
{
    __shared__ __align__(16) char u_raw[25600];
    __shared__ float cf[4][24], cv[4][24];
    __shared__ float partial[8][4][24];
    __shared__ int   cntp[4][4];
    __shared__ float aggL[4][24];
    __shared__ int   bestL[256];

    const int g = blockIdx.x;
    const int bb = g >> 5, e = (g >> 2) & 7, f1 = (g >> 1) & 1, f2 = g & 1;
    const int t = threadIdx.x;
    const int wi = t >> 4, hj = t & 15;
    const int p = (f1 * 16 + wi) * 32 + (f2 * 16 + hj);
    const size_t tok = (size_t)bb * 1024 + p;

    const bf16x8* src = (const bf16x8*)(FV + tok * 384);
    bf16x8 hf0 = src[e * 3 + 0], hf1 = src[e * 3 + 1], hf2 = src[e * 3 + 2];
    bf16x8 hv0 = src[24 + e * 3 + 0], hv1 = src[24 + e * 3 + 1], hv2 = src[24 + e * 3 + 2];

    bf16* lfv = (bf16*)u_raw;                    // [256][48]
    {
        bf16x8* row = (bf16x8*)(lfv + t * 48);
        row[0] = hf0; row[1] = hf1; row[2] = hf2;
        row[3] = hv0; row[4] = hv1; row[5] = hv2;
    }
    float freg[24];
#pragma unroll
    for (int j = 0; j < 8; ++j) {
        freg[j] = (float)hf0[j]; freg[8 + j] = (float)hf1[j]; freg[16 + j] = (float)hf2[j];
    }
    __syncthreads();

    if (t < 192) {
        const int team = t / 96;
        const int idx = t % 96;
        const int m = idx / 24, c = idx % 24;
        const int pw = m >> 1, ph = m & 1;
        float s = 0.f;
        for (int a = 0; a < 8; ++a) {
            const int nb = (pw * 8 + a) * 16 + ph * 8;
#pragma unroll
            for (int bj = 0; bj < 8; ++bj)
                s += (float)lfv[(nb + bj) * 48 + team * 24 + c];
        }
        if (team) cv[m][c] = s * (1.f / 64.f);
        else      cf[m][c] = s * (1.f / 64.f);
    }
    __syncthreads();

    float nrm = 0.f;
#pragma unroll
    for (int c = 0; c < 24; ++c) nrm += freg[c] * freg[c];
    const float invf = 1.f / fmaxf(sqrtf(nrm), 1e-12f);
    const float alpha = alpha_p[0], beta = beta_p[0];
    float bestv = -1.f; int best = 0;
#pragma unroll
    for (int m = 0; m < 4; ++m) {
        float d = 0.f, cs = 0.f;
#pragma unroll
        for (int c = 0; c < 24; ++c) {
            const float cfv = cf[m][c];
            d += cfv * freg[c];
            cs += cfv * cfv;
        }
        const float z = beta + alpha * d * (1.f / fmaxf(sqrtf(cs), 1e-12f)) * invf;
        const float sim = 1.f / (1.f + expf(-z));
        if (sim > bestv) { bestv = sim; best = m; }
    }

    {
        const unsigned long long q0 = __ballot(best == 0);
        const unsigned long long q1 = __ballot(best == 1);
        const unsigned long long q2 = __ballot(best == 2);
        const unsigned long long q3 = __ballot(best == 3);
        if ((t & 63) == 0) {
            const int w = t >> 6;
            cntp[w][0] = __popcll(q0); cntp[w][1] = __popcll(q1);
            cntp[w][2] = __popcll(q2); cntp[w][3] = __popcll(q3);
        }
    }

    float (*pvL)[25] = (float (*)[25])u_raw;
#pragma unroll
    for (int j = 0; j < 8; ++j) {
        pvL[t][j]      = bestv * (float)hv0[j];
        pvL[t][8 + j]  = bestv * (float)hv1[j];
        pvL[t][16 + j] = bestv * (float)hv2[j];
    }
    bestL[t] = best;
    __syncthreads();

    if (t < 192) {
        const int seg = t / 24, c = t % 24;
        float a0 = 0.f, a1 = 0.f, a2 = 0.f, a3 = 0.f;
        const int nb = seg * 32;
        for (int i = 0; i < 32; ++i) {
            const int n = nb + i;
            const int bm = bestL[n];
            const float x = pvL[n][c];
            a0 += (bm == 0) ? x : 0.f;
            a1 += (bm == 1) ? x : 0.f;
            a2 += (bm == 2) ? x : 0.f;
            a3 += (bm == 3) ? x : 0.f;
        }
        partial[seg][0][c] = a0; partial[seg][1][c] = a1;
        partial[seg][2][c] = a2; partial[seg][3][c] = a3;
    }
    __syncthreads();

    if (t < 96) {
        const int m = t / 24, c = t % 24;
        float s = 0.f;
#pragma unroll
        for (int seg = 0; seg < 8; ++seg) s += partial[seg][m][c];
        const int cnt = cntp[0][m] + cntp[1][m] + cntp[2][m] + cntp[3][m];
        aggL[m][c] = (s + cv[m][c]) / ((float)cnt + 1.f);
    }
    __syncthreads();

    const float sv = bestv; const int bm = best;
    bf16x8 z0, z1, z2;
#pragma unroll
    for (int j = 0; j < 8; ++j) {
        z0[j] = (bf16)(aggL[bm][j] * sv);
        z1[j] = (bf16)(aggL[bm][8 + j] * sv);
        z2[j] = (bf16)(aggL[bm][16 + j] * sv);
    }
    bf16x8* dst = (bf16x8*)(Y + tok * DIMC + e * 24);
    dst[0] = z0; dst[1] = z1; dst[2] = z2;
}

// ---------------- launch ----------------
extern "C" void kernel_launch(void* const* d_in, const int* in_sizes, int n_in,
                              void* d_out, int out_size, void* d_ws, size_t ws_size,
                              hipStream_t stream)
{
    (void)in_sizes; (void)n_in; (void)out_size; (void)ws_size;
    const float* x      = (const float*)d_in[0];
    const float* gn1_w  = (const float*)d_in[1];
    const float* gn1_b  = (const float*)d_in[2];
    const float* f_w    = (const float*)d_in[3];
    const float* f_b    = (const float*)d_in[4];
    const float* v_w    = (const float*)d_in[5];
    const float* v_b    = (const float*)d_in[6];
    const float* proj_w = (const float*)d_in[7];
    const float* proj_b = (const float*)d_in[8];
    const float* alpha  = (const float*)d_in[9];
    const float* beta   = (const float*)d_in[10];
    const float* ls1    = (const float*)d_in[11];
    const float* gn2_w  = (const float*)d_in[12];
    const float* gn2_b  = (const float*)d_in[13];
    const float* fc1_w  = (const float*)d_in[14];
    const float* fc1_b  = (const float*)d_in[15];
    const float* fc2_w  = (const float*)d_in[16];
    const float* fc2_b  = (const float*)d_in[17];
    const float* ls2    = (const float*)d_in[18];

    char* ws = (char*)d_ws;
    float2* part1 = (float2*)(ws + OFF_PART1);
    float2* part2 = (float2*)(ws + OFF_PART2);
    float* biasfv = (float*)(ws + OFF_BIASFV);
    bf16* Wfvp  = (bf16*)(ws + OFF_WFV);
    bf16* Wpjp  = (bf16*)(ws + OFF_WPJ);
    bf16* W1p   = (bf16*)(ws + OFF_W1P);
    bf16* W2p   = (bf16*)(ws + OFF_W2P);
    bf16* FVb   = (bf16*)(ws + OFF_FV);
    bf16* Yb    = (bf16*)(ws + OFF_Y);
    float* X1   = (float*)(ws + OFF_X1);
    float* out  = (float*)d_out;

    prep_stats<<<1600, 256, 0, stream>>>(f_w, v_w, proj_w, fc1_w, fc2_w, f_b, v_b,
                                         Wfvp, Wpjp, W1p, W2p, biasfv, x, part1);
    gemm_fv3<<<1024, 512, 0, stream>>>(x, part1, gn1_w, gn1_b, Wfvp, biasfv, FVb);
    cluster_k<<<2048, 256, 0, stream>>>(FVb, Yb, alpha, beta);
    gemm_pj<<<1024, 512, 0, stream>>>(Yb, Wpjp, proj_b, X1, x, ls1, part2);
    mlp_k<<<1024, 512, 0, stream>>>(X1, part2, gn2_w, gn2_b,
                                    W1p, fc1_b, W2p, fc2_b, ls2, out);
}

// Round 25
// 143.268 us; speedup vs baseline: 1.1710x; 1.0373x over previous
//
#include <hip/hip_runtime.h>
#include <math.h>

typedef __bf16 bf16;
typedef __bf16 bf16x8 __attribute__((ext_vector_type(8)));
typedef __bf16 bf16x4 __attribute__((ext_vector_type(4)));
typedef float  f32x4  __attribute__((ext_vector_type(4)));

union bfu { bf16x8 h; uint4 u; };

#define NSAMP 64
#define DIMC 192
#define SAMP_ELEMS 196608
#define M_TOK 65536

// ---- workspace layout (bytes) ----
constexpr size_t OFF_PART1  = 0;
constexpr size_t OFF_PART2  = 8192;
constexpr size_t OFF_BIASFV = 40960;
constexpr size_t OFF_WFV    = 43008;                // fragment-packed Wfv (147456 B)
constexpr size_t OFF_WPJ    = OFF_WFV + 147456;     // fragment-packed Wproj (73728 B)
constexpr size_t OFF_W1P    = OFF_WPJ + 73728;      // fragment-packed W1 (294912 B)
constexpr size_t OFF_W2P    = OFF_W1P + 294912;     // fragment-packed W2 (294912 B)
constexpr size_t OFF_R      = 1048576;
constexpr size_t OFF_FV     = OFF_R;
constexpr size_t OFF_Y      = OFF_R + 50331648;
constexpr size_t OFF_X1     = OFF_R + 100663296;    // X1 bf16 NHWC (25165824 B)

// ---------------- fused weight-prep + GN1 stats ----------------
// Blocks [0,576): weight prep (incl. Wpjp). Blocks [576,1600): GN1 stats over x.
__global__ __launch_bounds__(256) void prep_stats(
    const float* __restrict__ f_w, const float* __restrict__ v_w,
    const float* __restrict__ proj_w,
    const float* __restrict__ fc1_w, const float* __restrict__ fc2_w,
    const float* __restrict__ f_b, const float* __restrict__ v_b,
    bf16* __restrict__ Wfvp, bf16* __restrict__ Wpjp,
    bf16* __restrict__ W1p, bf16* __restrict__ W2p,
    float* __restrict__ biasfv,
    const float* __restrict__ X, float2* __restrict__ part)
{
    if (blockIdx.x >= 576) {
        const int blk = blockIdx.x - 576;
        const int b = blk >> 4, seg = blk & 15;
        const float4* p = (const float4*)(X + (size_t)b * SAMP_ELEMS + (size_t)seg * 12288);
        float s = 0.f, q = 0.f;
        for (int i = threadIdx.x; i < 3072; i += 256) {
            float4 v = p[i];
            s += v.x + v.y + v.z + v.w;
            q += v.x * v.x + v.y * v.y + v.z * v.z + v.w * v.w;
        }
        __shared__ float bs[256], bq[256];
        const int t = threadIdx.x;
        bs[t] = s; bq[t] = q; __syncthreads();
        for (int off = 128; off > 0; off >>= 1) {
            if (t < off) { bs[t] += bs[t + off]; bq[t] += bq[t + off]; }
            __syncthreads();
        }
        if (t == 0) part[b * 16 + seg] = make_float2(bs[0], bq[0]);
        return;
    }

    const int i = blockIdx.x * 256 + threadIdx.x;
    if (i < 73728) {
        const int e = i & 7, l = (i >> 3) & 63, f = i >> 9;
        const int ks = f % 6, wnf = f / 6;
        const int o = wnf * 16 + (l & 15);
        const int k = ks * 32 + (l >> 4) * 8 + e;
        Wfvp[i] = (bf16)(o < 192 ? f_w[o * 192 + k] : v_w[(o - 192) * 192 + k]);
    }
    if (i < 36864) {
        const int e = i & 7, l = (i >> 3) & 63, f = i >> 9;
        const int ks = f % 6, wnf = f / 6;
        const int o = wnf * 16 + (l & 15);
        const int k = ks * 32 + (l >> 4) * 8 + e;
        Wpjp[i] = (bf16)proj_w[o * 192 + k];
    }
    if (i < 147456) {
        const int e = i & 7, l = (i >> 3) & 63, f = i >> 9;
        const int ks = f % 6, pwj = f / 6;
        const int o = (pwj >> 2) * 64 + (pwj & 3) * 16 + (l & 15);
        const int k = ks * 32 + (l >> 4) * 8 + e;
        W1p[i] = (bf16)fc1_w[k * 768 + o];
    }
    if (i < 147456) {
        const int e = i & 7, l = (i >> 3) & 63, g = i >> 9;
        const int ks = g & 1, g1 = g >> 1;
        const int bqi = g1 % 3, jcw = g1 / 3;
        const int o = (jcw & 3) * 48 + bqi * 16 + (l & 15);
        const int k = (jcw >> 2) * 64 + ks * 32 + (l >> 4) * 8 + e;
        W2p[i] = (bf16)fc2_w[k * 192 + o];
    }
    if (i < 384) biasfv[i] = i < 192 ? f_b[i] : v_b[i - 192];
}

__device__ inline float2 gn_mv_n(const float2* __restrict__ part, int b, int n)
{
    float s = 0.f, q = 0.f;
    for (int i = 0; i < n; ++i) { float2 v = part[b * n + i]; s += v.x; q += v.y; }
    const float mean = s * (1.f / (float)SAMP_ELEMS);
    const float var = q * (1.f / (float)SAMP_ELEMS) - mean * mean;
    float2 r; r.x = mean; r.y = rsqrtf(var + 1e-5f);
    return r;
}

// ---------------- fused GN1 + f/v conv GEMM (R20-verified) ----------------
__global__ __launch_bounds__(512) void gemm_fv3(
    const float* __restrict__ X, const float2* __restrict__ part,
    const float* __restrict__ gw, const float* __restrict__ gb,
    const bf16* __restrict__ Wfvp, const float* __restrict__ bias,
    bf16* __restrict__ outb)
{
    __shared__ uint4 sA[64 * 24];
    const int t = threadIdx.x;
    const int m0 = blockIdx.x * 64;
    const int bb = m0 >> 10, p0 = m0 & 1023;
    const int lane = t & 63, wave = t >> 6;
    const int wm = wave >> 2, wn = wave & 3;
    const int lm = lane & 15, hi = lane >> 4;
    const float2 mv = gn_mv_n(part, bb, 16);

    bf16* sab = (bf16*)sA;
    for (int i = t; i < 3072; i += 512) {
        const int c = i >> 4, pq = i & 15;
        const float4 v = *(const float4*)(X + ((size_t)bb * DIMC + c) * 1024 + p0 + pq * 4);
        const float scale = gw[c] * mv.y;
        const float shift = gb[c] - mv.x * scale;
        const int ci = c >> 3, co = c & 7;
#pragma unroll
        for (int j = 0; j < 4; ++j) {
            const int r = pq * 4 + j;
            sab[(r * 24 + (ci ^ (r & 7))) * 8 + co] = (bf16)((&v.x)[j] * scale + shift);
        }
    }
    __syncthreads();

    const bf16x8* fa = (const bf16x8*)sA;
    const bf16x8* fw = (const bf16x8*)Wfvp;
    const int rA0 = wm * 32 + lm, rA1 = rA0 + 16;

    f32x4 acc[2][6] = {};
    bf16x8 wf[6];
#pragma unroll
    for (int nf = 0; nf < 6; ++nf)
        wf[nf] = fw[((wn * 6 + nf) * 6 + 0) * 64 + lane];

#pragma unroll
    for (int ks = 0; ks < 6; ++ks) {
        bf16x8 wfn[6];
        if (ks < 5) {
#pragma unroll
            for (int nf = 0; nf < 6; ++nf)
                wfn[nf] = fw[((wn * 6 + nf) * 6 + ks + 1) * 64 + lane];
        }
        const int cb = ks * 4 + hi;
        bf16x8 a0 = fa[rA0 * 24 + (cb ^ (rA0 & 7))];
        bf16x8 a1 = fa[rA1 * 24 + (cb ^ (rA1 & 7))];
        __builtin_amdgcn_s_setprio(1);
#pragma unroll
        for (int nf = 0; nf < 6; ++nf) {
            acc[0][nf] = __builtin_amdgcn_mfma_f32_16x16x32_bf16(a0, wf[nf], acc[0][nf], 0, 0, 0);
            acc[1][nf] = __builtin_amdgcn_mfma_f32_16x16x32_bf16(a1, wf[nf], acc[1][nf], 0, 0, 0);
        }
        __builtin_amdgcn_s_setprio(0);
        if (ks < 5) {
#pragma unroll
            for (int nf = 0; nf < 6; ++nf) wf[nf] = wfn[nf];
        }
    }

#pragma unroll
    for (int mt = 0; mt < 2; ++mt) {
#pragma unroll
        for (int nf = 0; nf < 6; ++nf) {
            f32x4 av = acc[mt][nf];
            const int nc = wn * 96 + nf * 16 + lm;
            const int mr = m0 + wm * 32 + mt * 16 + hi * 4;
            const float bv = bias[nc];
#pragma unroll
            for (int j = 0; j < 4; ++j)
                outb[(size_t)(mr + j) * 384 + nc] = (bf16)(av[j] + bv);
        }
    }
}

// ---------------- proj GEMM (R19 structure; X1 now stored bf16) ----------------
__global__ __launch_bounds__(512) void gemm_pj(
    const bf16* __restrict__ A, const bf16* __restrict__ Wpjp,
    const float* __restrict__ bias,
    bf16* __restrict__ outx1,
    const float* __restrict__ resid, const float* __restrict__ ls,
    float2* __restrict__ pstats)
{
    __shared__ __align__(16) char ubuf[49920];   // phase1: sA 24576 B; phase2: lx [192][65] f32
    __shared__ float rs[512], rq[512];
    uint4* sA = (uint4*)ubuf;
    const int t = threadIdx.x;
    const int m0 = blockIdx.x * 64;
    const int lane = t & 63, wave = t >> 6;
    const int wm = wave >> 2, wn = wave & 3;
    const int lm = lane & 15, hi = lane >> 4;

    for (int i = t; i < 64 * 24; i += 512) {
        const int r = i / 24, ci = i % 24;
        sA[r * 24 + (ci ^ (r & 7))] = *(const uint4*)(A + (size_t)(m0 + r) * 192 + ci * 8);
    }
    __syncthreads();

    const bf16x8* fa = (const bf16x8*)sA;
    const bf16x8* fw = (const bf16x8*)Wpjp;
    const int rA0 = wm * 32 + lm, rA1 = rA0 + 16;

    f32x4 acc[2][3] = {};
    bf16x8 wf[3];
#pragma unroll
    for (int nf = 0; nf < 3; ++nf)
        wf[nf] = fw[((wn * 3 + nf) * 6 + 0) * 64 + lane];

#pragma unroll
    for (int ks = 0; ks < 6; ++ks) {
        bf16x8 wfn[3];
        if (ks < 5) {
#pragma unroll
            for (int nf = 0; nf < 3; ++nf)
                wfn[nf] = fw[((wn * 3 + nf) * 6 + ks + 1) * 64 + lane];
        }
        const int cb = ks * 4 + hi;
        bf16x8 a0 = fa[rA0 * 24 + (cb ^ (rA0 & 7))];
        bf16x8 a1 = fa[rA1 * 24 + (cb ^ (rA1 & 7))];
        __builtin_amdgcn_s_setprio(1);
#pragma unroll
        for (int nf = 0; nf < 3; ++nf) {
            acc[0][nf] = __builtin_amdgcn_mfma_f32_16x16x32_bf16(a0, wf[nf], acc[0][nf], 0, 0, 0);
            acc[1][nf] = __builtin_amdgcn_mfma_f32_16x16x32_bf16(a1, wf[nf], acc[1][nf], 0, 0, 0);
        }
        __builtin_amdgcn_s_setprio(0);
        if (ks < 5) {
#pragma unroll
            for (int nf = 0; nf < 3; ++nf) wf[nf] = wfn[nf];
        }
    }

    __syncthreads();
    float* lx = (float*)ubuf;            // [192][65]
    {
        const int bb0 = m0 >> 10, p0 = m0 & 1023;
        for (int i = t; i < 192 * 16; i += 512) {
            const int r = i >> 4, c4 = (i & 15) * 4;
            const float4 v = *(const float4*)(resid + ((size_t)bb0 * DIMC + r) * 1024 + p0 + c4);
            lx[r * 65 + c4 + 0] = v.x;
            lx[r * 65 + c4 + 1] = v.y;
            lx[r * 65 + c4 + 2] = v.z;
            lx[r * 65 + c4 + 3] = v.w;
        }
    }
    __syncthreads();

    float ps = 0.f, pq = 0.f;
#pragma unroll
    for (int mt = 0; mt < 2; ++mt) {
#pragma unroll
        for (int nf = 0; nf < 3; ++nf) {
            f32x4 av = acc[mt][nf];
            const int nc = wn * 48 + nf * 16 + lm;
            const int mr = m0 + wm * 32 + mt * 16 + hi * 4;
            const float bv = bias[nc];
#pragma unroll
            for (int j = 0; j < 4; ++j) {
                const int m = mr + j;
                const float v = av[j] + bv;
                const float xv = lx[nc * 65 + (m - m0)];
                const float x1 = xv + ls[nc] * v;
                outx1[(size_t)m * DIMC + nc] = (bf16)x1;   // X1 stored bf16
                ps += x1; pq += x1 * x1;                   // stats from exact f32
            }
        }
    }

    rs[t] = ps; rq[t] = pq; __syncthreads();
    for (int off = 256; off > 0; off >>= 1) {
        if (t < off) { rs[t] += rs[t + off]; rq[t] += rq[t + off]; }
        __syncthreads();
    }
    if (t == 0) {
        const int bb = blockIdx.x >> 4;
        const int slot = blockIdx.x & 15;
        pstats[bb * 16 + slot] = make_float2(rs[0], rq[0]);
    }
}

// ---------------- fused MLP: producer/consumer, 2 chunks per barrier (R22-verified) ----------------
// X1 now bf16 NHWC: staging reads bf16x8 (half the bytes), epilogue residual reads bf16.
__global__ __launch_bounds__(512) void mlp_k(
    const bf16* __restrict__ X1b, const float2* __restrict__ part,
    const float* __restrict__ gw, const float* __restrict__ gb,
    const bf16* __restrict__ W1p, const float* __restrict__ b1,
    const bf16* __restrict__ W2p, const float* __restrict__ b2,
    const float* __restrict__ ls, float* __restrict__ out)
{
    __shared__ uint4 sA[64 * 24];           // 24 KB
    __shared__ bf16  sH[2][2][64 * 64];     // 32 KB: [pair parity][chunk-in-pair]

    const int t = threadIdx.x;
    const int m0 = blockIdx.x * 64;
    const int bb = m0 >> 10;
    const int lane = t & 63, wv = t >> 6;     // 0..7
    const int lm = lane & 15, hi = lane >> 4;
    const int lsw = lm & 7;

    const float2 mv = gn_mv_n(part, bb, 16);
    const bf16x8* fW1 = (const bf16x8*)W1p;
    const bf16x8* fW2 = (const bf16x8*)W2p;

    for (int cid = t; cid < 1536; cid += 512) {
        const int r = cid / 24, ci = cid % 24;
        const int c0 = ci * 8;
        const bf16x8 xv = *(const bf16x8*)(X1b + (size_t)(m0 + r) * 192 + c0);
        const float4 w0 = *(const float4*)(gw + c0);
        const float4 w1 = *(const float4*)(gw + c0 + 4);
        const float4 g0 = *(const float4*)(gb + c0);
        const float4 g1 = *(const float4*)(gb + c0 + 4);
        bfu o;
        o.h[0] = (bf16)(((float)xv[0] - mv.x) * mv.y * w0.x + g0.x);
        o.h[1] = (bf16)(((float)xv[1] - mv.x) * mv.y * w0.y + g0.y);
        o.h[2] = (bf16)(((float)xv[2] - mv.x) * mv.y * w0.z + g0.z);
        o.h[3] = (bf16)(((float)xv[3] - mv.x) * mv.y * w0.w + g0.w);
        o.h[4] = (bf16)(((float)xv[4] - mv.x) * mv.y * w1.x + g1.x);
        o.h[5] = (bf16)(((float)xv[5] - mv.x) * mv.y * w1.y + g1.y);
        o.h[6] = (bf16)(((float)xv[6] - mv.x) * mv.y * w1.z + g1.z);
        o.h[7] = (bf16)(((float)xv[7] - mv.x) * mv.y * w1.w + g1.w);
        sA[r * 24 + (ci ^ (r & 7))] = o.u;
    }
    __syncthreads();

    const bf16x8* fa = (const bf16x8*)sA;

    if (wv < 4) {
        // ---------------- PRODUCER: hid cols pw*16+lm of each chunk ----------------
        const int pw = wv;
        bf16x8 w1f[6];
#pragma unroll
        for (int ks = 0; ks < 6; ++ks)
            w1f[ks] = fW1[(pw * 6 + ks) * 64 + lane];
        const int hcs = pw * 2 + (lm >> 3), hco = lm & 7;

        for (int pp = 0; pp <= 6; ++pp) {
            if (pp < 6) {
#pragma unroll
                for (int c2 = 0; c2 < 2; ++c2) {
                    const int jj = 2 * pp + c2;
                    f32x4 h[4];
#pragma unroll
                    for (int a = 0; a < 4; ++a) h[a] = (f32x4){0, 0, 0, 0};
                    __builtin_amdgcn_s_setprio(1);
#pragma unroll
                    for (int ks = 0; ks < 6; ++ks) {
                        const int cb = ks * 4 + hi;
                        bf16x8 a0 = fa[(lm)      * 24 + (cb ^ lsw)];
                        bf16x8 a1 = fa[(16 + lm) * 24 + (cb ^ lsw)];
                        bf16x8 a2 = fa[(32 + lm) * 24 + (cb ^ lsw)];
                        bf16x8 a3 = fa[(48 + lm) * 24 + (cb ^ lsw)];
                        h[0] = __builtin_amdgcn_mfma_f32_16x16x32_bf16(a0, w1f[ks], h[0], 0, 0, 0);
                        h[1] = __builtin_amdgcn_mfma_f32_16x16x32_bf16(a1, w1f[ks], h[1], 0, 0, 0);
                        h[2] = __builtin_amdgcn_mfma_f32_16x16x32_bf16(a2, w1f[ks], h[2], 0, 0, 0);
                        h[3] = __builtin_amdgcn_mfma_f32_16x16x32_bf16(a3, w1f[ks], h[3], 0, 0, 0);
                    }
                    __builtin_amdgcn_s_setprio(0);

                    if (jj < 11) {
#pragma unroll
                        for (int ks = 0; ks < 6; ++ks)
                            w1f[ks] = fW1[(((jj + 1) * 4 + pw) * 6 + ks) * 64 + lane];
                    }

                    bf16* sh = sH[pp & 1][c2];
                    const float b1v = b1[jj * 64 + pw * 16 + lm];
#pragma unroll
                    for (int mfr = 0; mfr < 4; ++mfr) {
#pragma unroll
                        for (int q = 0; q < 4; ++q) {
                            const int m = mfr * 16 + hi * 4 + q;
                            const float vv = h[mfr][q] + b1v;
                            const float g = vv * __builtin_amdgcn_rcpf(1.f + __expf(-1.702f * vv));
                            sh[m * 64 + ((hcs ^ (m & 7)) << 3) + hco] = (bf16)g;
                        }
                    }
                }
            }
            __syncthreads();
        }
    } else {
        // ---------------- CONSUMER: out cols cw*48 .. +48 ----------------
        const int cw = wv - 4;
        f32x4 oa[4][3];
#pragma unroll
        for (int a = 0; a < 4; ++a)
#pragma unroll
            for (int bq = 0; bq < 3; ++bq) oa[a][bq] = (f32x4){0, 0, 0, 0};

        bf16x8 w2f[2][3][2];   // [chunk-in-pair][bqi][ks], prefetch chunks 0,1
#pragma unroll
        for (int c2 = 0; c2 < 2; ++c2)
#pragma unroll
            for (int bqi = 0; bqi < 3; ++bqi)
#pragma unroll
                for (int ks = 0; ks < 2; ++ks)
                    w2f[c2][bqi][ks] = fW2[(((c2 * 4 + cw) * 3 + bqi) * 2 + ks) * 64 + lane];

        for (int pp = 0; pp <= 6; ++pp) {
            if (pp >= 1) {
#pragma unroll
                for (int c2 = 0; c2 < 2; ++c2) {
                    const bf16x8* fh = (const bf16x8*)sH[(pp - 1) & 1][c2];
                    __builtin_amdgcn_s_setprio(1);
#pragma unroll
                    for (int ks = 0; ks < 2; ++ks) {
                        const int cc = ks * 4 + hi;
#pragma unroll
                        for (int mfr = 0; mfr < 4; ++mfr) {
                            bf16x8 ah = fh[(mfr * 16 + lm) * 8 + (cc ^ lsw)];
                            oa[mfr][0] = __builtin_amdgcn_mfma_f32_16x16x32_bf16(ah, w2f[c2][0][ks], oa[mfr][0], 0, 0, 0);
                            oa[mfr][1] = __builtin_amdgcn_mfma_f32_16x16x32_bf16(ah, w2f[c2][1][ks], oa[mfr][1], 0, 0, 0);
                            oa[mfr][2] = __builtin_amdgcn_mfma_f32_16x16x32_bf16(ah, w2f[c2][2][ks], oa[mfr][2], 0, 0, 0);
                        }
                    }
                    __builtin_amdgcn_s_setprio(0);
                }

                // prefetch next pair's W2 fragments (chunks 2pp, 2pp+1)
                if (pp < 6) {
#pragma unroll
                    for (int c2 = 0; c2 < 2; ++c2)
#pragma unroll
                        for (int bqi = 0; bqi < 3; ++bqi)
#pragma unroll
                            for (int ks = 0; ks < 2; ++ks)
                                w2f[c2][bqi][ks] = fW2[((((2 * pp + c2) * 4 + cw) * 3 + bqi) * 2 + ks) * 64 + lane];
                }
            }
            __syncthreads();
        }

        // epilogue (consumers only): out(NCHW) = X1 + ls2 * (acc + b2)
#pragma unroll
        for (int mfr = 0; mfr < 4; ++mfr) {
#pragma unroll
            for (int bqi = 0; bqi < 3; ++bqi) {
                f32x4 av = oa[mfr][bqi];
                const int nc = cw * 48 + bqi * 16 + lm;
                const int mr = mfr * 16 + hi * 4;
                const float b2v = b2[nc], lsv = ls[nc];
                const bf16* xp = X1b + (size_t)(m0 + mr) * 192 + nc;
                float4 ov;
                ov.x = (float)xp[0]   + lsv * (av[0] + b2v);
                ov.y = (float)xp[192] + lsv * (av[1] + b2v);
                ov.z = (float)xp[384] + lsv * (av[2] + b2v);
                ov.w = (float)xp[576] + lsv * (av[3] + b2v);
                *(float4*)(out + ((size_t)bb * DIMC + nc) * 1024 + (m0 & 1023) + mr) = ov;
            }
        }
    }
}

// ---------------- cluster (R15-verified) ----------------
__global__ __launch_bounds__(256) void cluster_k(
    const bf16* __restrict__ FV, bf16* __restrict__ Y,
    const float* __restrict__ alpha_p, const float* __restrict__ beta_p)
{
    __shared__ __align__(16) char u_raw[25600];
    __shared__ float cf[4][24], cv[4][24];
    __shared__ float partial[8][4][24];
    __shared__ int   cntp[4][4];
    __shared__ float aggL[4][24];
    __shared__ int   bestL[256];

    const int g = blockIdx.x;
    const int bb = g >> 5, e = (g >> 2) & 7, f1 = (g >> 1) & 1, f2 = g & 1;
    const int t = threadIdx.x;
    const int wi = t >> 4, hj = t & 15;
    const int p = (f1 * 16 + wi) * 32 + (f2 * 16 + hj);
    const size_t tok = (size_t)bb * 1024 + p;

    const bf16x8* src = (const bf16x8*)(FV + tok * 384);
    bf16x8 hf0 = src[e * 3 + 0], hf1 = src[e * 3 + 1], hf2 = src[e * 3 + 2];
    bf16x8 hv0 = src[24 + e * 3 + 0], hv1 = src[24 + e * 3 + 1], hv2 = src[24 + e * 3 + 2];

    bf16* lfv = (bf16*)u_raw;                    // [256][48]
    {
        bf16x8* row = (bf16x8*)(lfv + t * 48);
        row[0] = hf0; row[1] = hf1; row[2] = hf2;
        row[3] = hv0; row[4] = hv1; row[5] = hv2;
    }
    float freg[24];
#pragma unroll
    for (int j = 0; j < 8; ++j) {
        freg[j] = (float)hf0[j]; freg[8 + j] = (float)hf1[j]; freg[16 + j] = (float)hf2[j];
    }
    __syncthreads();

    if (t < 192) {
        const int team = t / 96;
        const int idx = t % 96;
        const int m = idx / 24, c = idx % 24;
        const int pw = m >> 1, ph = m & 1;
        float s = 0.f;
        for (int a = 0; a < 8; ++a) {
            const int nb = (pw * 8 + a) * 16 + ph * 8;
#pragma unroll
            for (int bj = 0; bj < 8; ++bj)
                s += (float)lfv[(nb + bj) * 48 + team * 24 + c];
        }
        if (team) cv[m][c] = s * (1.f / 64.f);
        else      cf[m][c] = s * (1.f / 64.f);
    }
    __syncthreads();

    float nrm = 0.f;
#pragma unroll
    for (int c = 0; c < 24; ++c) nrm += freg[c] * freg[c];
    const float invf = 1.f / fmaxf(sqrtf(nrm), 1e-12f);
    const float alpha = alpha_p[0], beta = beta_p[0];
    float bestv = -1.f; int best = 0;
#pragma unroll
    for (int m = 0; m < 4; ++m) {
        float d = 0.f, cs = 0.f;
#pragma unroll
        for (int c = 0; c < 24; ++c) {
            const float cfv = cf[m][c];
            d += cfv * freg[c];
            cs += cfv * cfv;
        }
        const float z = beta + alpha * d * (1.f / fmaxf(sqrtf(cs), 1e-12f)) * invf;
        const float sim = 1.f / (1.f + expf(-z));
        if (sim > bestv) { bestv = sim; best = m; }
    }

    {
        const unsigned long long q0 = __ballot(best == 0);
        const unsigned long long q1 = __ballot(best == 1);
        const unsigned long long q2 = __ballot(best == 2);
        const unsigned long long q3 = __ballot(best == 3);
        if ((t & 63) == 0) {
            const int w = t >> 6;
            cntp[w][0] = __popcll(q0); cntp[w][1] = __popcll(q1);
            cntp[w][2] = __popcll(q2); cntp[w][3] = __popcll(q3);
        }
    }

    float (*pvL)[25] = (float (*)[25])u_raw;
#pragma unroll
    for (int j = 0; j < 8; ++j) {
        pvL[t][j]      = bestv * (float)hv0[j];
        pvL[t][8 + j]  = bestv * (float)hv1[j];
        pvL[t][16 + j] = bestv * (float)hv2[j];
    }
    bestL[t] = best;
    __syncthreads();

    if (t < 192) {
        const int seg = t / 24, c = t % 24;
        float a0 = 0.f, a1 = 0.f, a2 = 0.f, a3 = 0.f;
        const int nb = seg * 32;
        for (int i = 0; i < 32; ++i) {
            const int n = nb + i;
            const int bm = bestL[n];
            const float x = pvL[n][c];
            a0 += (bm == 0) ? x : 0.f;
            a1 += (bm == 1) ? x : 0.f;
            a2 += (bm == 2) ? x : 0.f;
            a3 += (bm == 3) ? x : 0.f;
        }
        partial[seg][0][c] = a0; partial[seg][1][c] = a1;
        partial[seg][2][c] = a2; partial[seg][3][c] = a3;
    }
    __syncthreads();

    if (t < 96) {
        const int m = t / 24, c = t % 24;
        float s = 0.f;
#pragma unroll
        for (int seg = 0; seg < 8; ++seg) s += partial[seg][m][c];
        const int cnt = cntp[0][m] + cntp[1][m] + cntp[2][m] + cntp[3][m];
        aggL[m][c] = (s + cv[m][c]) / ((float)cnt + 1.f);
    }
    __syncthreads();

    const float sv = bestv; const int bm = best;
    bf16x8 z0, z1, z2;
#pragma unroll
    for (int j = 0; j < 8; ++j) {
        z0[j] = (bf16)(aggL[bm][j] * sv);
        z1[j] = (bf16)(aggL[bm][8 + j] * sv);
        z2[j] = (bf16)(aggL[bm][16 + j] * sv);
    }
    bf16x8* dst = (bf16x8*)(Y + tok * DIMC + e * 24);
    dst[0] = z0; dst[1] = z1; dst[2] = z2;
}

// ---------------- launch ----------------
extern "C" void kernel_launch(void* const* d_in, const int* in_sizes, int n_in,
                              void* d_out, int out_size, void* d_ws, size_t ws_size,
                              hipStream_t stream)
{
    (void)in_sizes; (void)n_in; (void)out_size; (void)ws_size;
    const float* x      = (const float*)d_in[0];
    const float* gn1_w  = (const float*)d_in[1];
    const float* gn1_b  = (const float*)d_in[2];
    const float* f_w    = (const float*)d_in[3];
    const float* f_b    = (const float*)d_in[4];
    const float* v_w    = (const float*)d_in[5];
    const float* v_b    = (const float*)d_in[6];
    const float* proj_w = (const float*)d_in[7];
    const float* proj_b = (const float*)d_in[8];
    const float* alpha  = (const float*)d_in[9];
    const float* beta   = (const float*)d_in[10];
    const float* ls1    = (const float*)d_in[11];
    const float* gn2_w  = (const float*)d_in[12];
    const float* gn2_b  = (const float*)d_in[13];
    const float* fc1_w  = (const float*)d_in[14];
    const float* fc1_b  = (const float*)d_in[15];
    const float* fc2_w  = (const float*)d_in[16];
    const float* fc2_b  = (const float*)d_in[17];
    const float* ls2    = (const float*)d_in[18];

    char* ws = (char*)d_ws;
    float2* part1 = (float2*)(ws + OFF_PART1);
    float2* part2 = (float2*)(ws + OFF_PART2);
    float* biasfv = (float*)(ws + OFF_BIASFV);
    bf16* Wfvp  = (bf16*)(ws + OFF_WFV);
    bf16* Wpjp  = (bf16*)(ws + OFF_WPJ);
    bf16* W1p   = (bf16*)(ws + OFF_W1P);
    bf16* W2p   = (bf16*)(ws + OFF_W2P);
    bf16* FVb   = (bf16*)(ws + OFF_FV);
    bf16* Yb    = (bf16*)(ws + OFF_Y);
    bf16* X1b   = (bf16*)(ws + OFF_X1);
    float* out  = (float*)d_out;

    prep_stats<<<1600, 256, 0, stream>>>(f_w, v_w, proj_w, fc1_w, fc2_w, f_b, v_b,
                                         Wfvp, Wpjp, W1p, W2p, biasfv, x, part1);
    gemm_fv3<<<1024, 512, 0, stream>>>(x, part1, gn1_w, gn1_b, Wfvp, biasfv, FVb);
    cluster_k<<<2048, 256, 0, stream>>>(FVb, Yb, alpha, beta);
    gemm_pj<<<1024, 512, 0, stream>>>(Yb, Wpjp, proj_b, X1b, x, ls1, part2);
    mlp_k<<<1024, 512, 0, stream>>>(X1b, part2, gn2_w, gn2_b,
                                    W1p, fc1_b, W2p, fc2_b, ls2, out);
}